// Round 7
// baseline (213.806 us; speedup 1.0000x reference)
//
#include <hip/hip_runtime.h>
#include <math.h>

// LeNet-ish forward, fp32, B=8192.
// conv1+pool folded into stride-2 6x6 conv (w6 = W1 (*) ones(2,2), /4 at use).
// conv1 emits S1 (2x2 window-sum of its sigmoid output) into LDS; conv2
// (S-trick) consumes it in-kernel. h2 stored interleaved [blk][320][8] so the
// FC kernel can stage a transposed activation tile with f4 ops.
// FC: 32 img/block, 4out x 4img register tiles, 8-deep manual weight prefetch
// (compiler won't pipeline global loads on its own - r4/r6 evidence: VGPR 20,
// 400cy serialized per iteration).
//
// ws: [w6 4KB][w2q 32KB][L2p 64KB][h2i: B*320 f32 interleaved]

__device__ __forceinline__ float sigf(float v) {
    return 1.0f / (1.0f + __expf(-v));
}

// --- K0: prep. w6[ky][c][8] from W1; w2q repack; L2 pad 84->88. ---
__global__ void k_prep(const float* __restrict__ W1, const float* __restrict__ W2,
                       const float* __restrict__ L2, float* __restrict__ w6,
                       float* __restrict__ w2q, float* __restrict__ L2p) {
    int i = blockIdx.x * 256 + threadIdx.x;
    if (i < 5000) {
        int kx = i % 5, t = i / 5;
        int ky = t % 5, t2 = t / 5;
        int ic = t2 % 10, c = t2 / 10;
        w2q[((ic * 5 + ky) * 20 + c) * 5 + kx] = W2[i];
    }
    int j = i - 5000;
    if (j >= 0 && j < 10080) L2p[(j / 84) * 88 + (j % 84)] = L2[j];
    int k = i - 15080;
    if (k >= 0 && k < 480) {
        int kx = k % 8, t = k / 8;
        int c = t % 10, ky = t / 10;
        float v = 0.f;
        if (kx < 6) {
            for (int dy = 0; dy < 2; ++dy)
                for (int dx = 0; dx < 2; ++dx) {
                    int sy = ky - dy, sx = kx - dx;
                    if (sy >= 0 && sy < 5 && sx >= 0 && sx < 5)
                        v += W1[c * 25 + sy * 5 + sx];
                }
        }
        w6[k] = v;
    }
}

// --- K1: fused convs. 512 threads, 8 img/block, 1024 blocks. ---
// Phase B (conv1): wave = image; lane = (cc<5: channel pair, py<12); 60/64.
//   acc[2][12]: all 12 px in-thread -> horizontal pool-pair in-thread,
//   vertical via shfl_down(,1) (lane+1 = same cc, py+1).
// Phase C (conv2): threads 0..159 packed: (im8, cg5, py4), acc[4oc][4px].
#define S1STR 1348  // 1348%32==4 -> image slabs bank-staggered

__global__ __launch_bounds__(512, 4) void k_convs(
    const float* __restrict__ x, const float* __restrict__ w6g,
    const float* __restrict__ b1, const float* __restrict__ w2qg,
    const float* __restrict__ b2, float* __restrict__ h2i) {
    __shared__ float S1t[8 * S1STR];   // 43136 B
    __shared__ float wq1[480];         // [ky6][ch10][8]
    __shared__ float w2s[5000];        // [icky50][c20][kx5]
    __shared__ float bs1[10];
    __shared__ float bs2[20];          // total 65176 B

    const int tid = threadIdx.x;
    for (int i = tid; i < 480; i += 512) wq1[i] = w6g[i];
    for (int i = tid; i < 5000; i += 512) w2s[i] = w2qg[i];
    if (tid < 10) bs1[tid] = b1[tid];
    if (tid >= 32 && tid < 52) bs2[tid - 32] = b2[tid - 32];
    __syncthreads();

    const long img0 = (long)blockIdx.x * 8;

    // ---- phase B ----
    {
        const int im = tid >> 6, l = tid & 63;
        if (l < 60) {
            const int cc = l / 12, py = l % 12;
            const int ch0 = cc * 2;
            float acc0[12], acc1[12];
#pragma unroll
            for (int p = 0; p < 12; ++p) { acc0[p] = 0.f; acc1[p] = 0.f; }

            const float* xim = x + (img0 + im) * 784;
#pragma unroll
            for (int ky = 0; ky < 6; ++ky) {
                const int r = 2 * py + ky;
                union { float4 v[7]; float f[28]; } R;
                const float4* rp = (const float4*)(xim + r * 28);
#pragma unroll
                for (int q = 0; q < 7; ++q) R.v[q] = rp[q];
                union { float4 v[2]; float f[8]; } W0, W1;
                const float* wb = &wq1[(ky * 10 + ch0) * 8];
                W0.v[0] = *(const float4*)(wb);
                W0.v[1] = *(const float4*)(wb + 4);
                W1.v[0] = *(const float4*)(wb + 8);
                W1.v[1] = *(const float4*)(wb + 12);
#pragma unroll
                for (int kx = 0; kx < 6; ++kx) {
                    const float w0 = W0.f[kx], w1 = W1.f[kx];
#pragma unroll
                    for (int px = 0; px < 12; ++px) {
                        const float xv = R.f[2 * px + kx];
                        acc0[px] += xv * w0;
                        acc1[px] += xv * w1;
                    }
                }
            }

#define FINISH_CH(ACC, CH)                                                   \
            {                                                                \
                float h[12];                                                 \
                _Pragma("unroll")                                            \
                for (int px = 0; px < 12; ++px)                              \
                    h[px] = sigf(ACC[px] * 0.25f + bs1[CH]);                 \
                float hh[11];                                                \
                _Pragma("unroll")                                            \
                for (int t = 0; t < 11; ++t) hh[t] = h[t] + h[t + 1];        \
                float o[12];                                                 \
                _Pragma("unroll")                                            \
                for (int t = 0; t < 11; ++t)                                 \
                    o[t] = hh[t] + __shfl_down(hh[t], 1, 64);                \
                o[11] = 0.f;                                                 \
                if (py < 11) {                                               \
                    float* sp = S1t + im * S1STR + (CH) * 132 + py * 12;     \
                    ((float4*)sp)[0] = make_float4(o[0], o[1], o[2], o[3]);  \
                    ((float4*)sp)[1] = make_float4(o[4], o[5], o[6], o[7]);  \
                    ((float4*)sp)[2] = make_float4(o[8], o[9], o[10], o[11]);\
                }                                                            \
            }
            FINISH_CH(acc0, ch0)
            FINISH_CH(acc1, ch0 + 1)
#undef FINISH_CH
        }
    }
    __syncthreads();

    // ---- phase C ----
    if (tid < 160) {
        const int im = tid / 20, r2 = tid % 20, cg = r2 / 4, py = r2 % 4;
        float acc[4][4];
#pragma unroll
        for (int a = 0; a < 4; ++a)
#pragma unroll
            for (int b = 0; b < 4; ++b) acc[a][b] = 0.f;

        const float* s1 = S1t + im * S1STR;
        for (int ic = 0; ic < 10; ++ic) {
#pragma unroll
            for (int ky = 0; ky < 5; ++ky) {
                union { float4 v[3]; float f[12]; } R;
                const float4* rp = (const float4*)(s1 + ic * 132 + (2 * py + ky) * 12);
                R.v[0] = rp[0]; R.v[1] = rp[1]; R.v[2] = rp[2];
                union { float4 v[5]; float f[20]; } W;
                const float4* wp = (const float4*)(w2s + (ic * 5 + ky) * 100 + cg * 20);
#pragma unroll
                for (int q = 0; q < 5; ++q) W.v[q] = wp[q];
#pragma unroll
                for (int cc = 0; cc < 4; ++cc)
#pragma unroll
                    for (int kx = 0; kx < 5; ++kx) {
                        const float wv = W.f[cc * 5 + kx];
#pragma unroll
                        for (int px = 0; px < 4; ++px)
                            acc[cc][px] += R.f[2 * px + kx] * wv;
                    }
            }
        }

        float* outp = h2i + (long)blockIdx.x * 2560 + im;
#pragma unroll
        for (int cc = 0; cc < 4; ++cc) {
            const float bv = bs2[cg * 4 + cc];
#pragma unroll
            for (int px = 0; px < 4; ++px) {
                const int row = (cg * 4 + cc) * 16 + py * 4 + px;
                outp[row * 8] = sigf(acc[cc][px] * 0.25f + bv);
            }
        }
    }
}

// --- K2: FC chain. 32 img/block, grid 256, 256 threads. ---
// h2t transposed in LDS [320 rows][36 cols(img)] -> activation read = 1 f4.
// Weight streams use 8-deep rotating prefetch (static indices) to force ILP.
__global__ __launch_bounds__(256) void k_fc(
    const float* __restrict__ h2i, const float* __restrict__ L1,
    const float* __restrict__ Lb1, const float* __restrict__ L2p,
    const float* __restrict__ Lb2, const float* __restrict__ L3,
    const float* __restrict__ Lb3, float* __restrict__ out) {
    __shared__ float big[11520];      // h2t[320][36]; later g2t[84][36] + L3s@8192
    __shared__ float g1t[120 * 36];   // 17280 B ; total 63360 B

    const int tid = threadIdx.x;
    const long img0 = (long)blockIdx.x * 32;

    // stage h2t[row][im32] from h2i[cb][row][im8] (f4 in, f4 out)
    for (int i = tid; i < 2560; i += 256) {
        const int row = i >> 3, k = i & 7, cb = k >> 1, hf = k & 1;
        float4 v = *(const float4*)(h2i + ((long)(blockIdx.x * 4 + cb) * 320 + row) * 8 + hf * 4);
        *(float4*)&big[row * 36 + cb * 8 + hf * 4] = v;
    }
    __syncthreads();

    const int jg = tid & 31, og = tid >> 5, i0 = og * 4;

    // ---- FC1: 320 -> 120 ----
    {
        const int jc = jg < 30 ? jg : 29;
        union { float4 v; float f[4]; } bv;
        bv.v = *(const float4*)(Lb1 + jc * 4);
        float acc[4][4];
#pragma unroll
        for (int q = 0; q < 4; ++q)
#pragma unroll
            for (int p = 0; p < 4; ++p) acc[q][p] = bv.f[q];

        const float* wbase = L1 + jc * 4;
        float4 wb[8];
#pragma unroll
        for (int k = 0; k < 8; ++k) wb[k] = *(const float4*)(wbase + k * 120);
        for (int ii = 0; ii < 320; ii += 8) {
#pragma unroll
            for (int k = 0; k < 8; ++k) {
                const int i = ii + k;
                union { float4 v; float f[4]; } w;
                w.v = wb[k];
                const int ip = (i + 8 < 320) ? i + 8 : i;
                wb[k] = *(const float4*)(wbase + ip * 120);
                union { float4 v; float f[4]; } h;
                h.v = *(const float4*)&big[i * 36 + i0];
#pragma unroll
                for (int q = 0; q < 4; ++q) {
                    acc[q][0] += w.f[q] * h.f[0];
                    acc[q][1] += w.f[q] * h.f[1];
                    acc[q][2] += w.f[q] * h.f[2];
                    acc[q][3] += w.f[q] * h.f[3];
                }
            }
        }
        if (jg < 30) {
#pragma unroll
            for (int q = 0; q < 4; ++q)
#pragma unroll
                for (int p = 0; p < 4; ++p)
                    g1t[(jg * 4 + q) * 36 + i0 + p] = sigf(acc[q][p]);
        }
    }
    __syncthreads();

    // ---- FC2: 120 -> 84 (jg<21) ; L3/Lb3 staging (jg>=21) ----
    if (jg < 21) {
        union { float4 v; float f[4]; } bv;
        bv.v = *(const float4*)(Lb2 + jg * 4);
        float acc[4][4];
#pragma unroll
        for (int q = 0; q < 4; ++q)
#pragma unroll
            for (int p = 0; p < 4; ++p) acc[q][p] = bv.f[q];

        const float* wbase = L2p + jg * 4;
        float4 wb[8];
#pragma unroll
        for (int k = 0; k < 8; ++k) wb[k] = *(const float4*)(wbase + k * 88);
        for (int ii = 0; ii < 120; ii += 8) {
#pragma unroll
            for (int k = 0; k < 8; ++k) {
                const int i = ii + k;
                union { float4 v; float f[4]; } w;
                w.v = wb[k];
                const int ip = (i + 8 < 120) ? i + 8 : i;
                wb[k] = *(const float4*)(wbase + ip * 88);
                union { float4 v; float f[4]; } h;
                h.v = *(const float4*)&g1t[i * 36 + i0];
#pragma unroll
                for (int q = 0; q < 4; ++q) {
                    acc[q][0] += w.f[q] * h.f[0];
                    acc[q][1] += w.f[q] * h.f[1];
                    acc[q][2] += w.f[q] * h.f[2];
                    acc[q][3] += w.f[q] * h.f[3];
                }
            }
        }
#pragma unroll
        for (int q = 0; q < 4; ++q)
#pragma unroll
            for (int p = 0; p < 4; ++p)
                big[(jg * 4 + q) * 36 + i0 + p] = sigf(acc[q][p]);  // g2t
    } else {
        const int sid = og * 11 + (jg - 21);  // 0..87
        for (int i = sid; i < 840; i += 88) big[8192 + i] = L3[i];
        if (sid < 10) big[8192 + 840 + sid] = Lb3[sid];
    }
    __syncthreads();

    // ---- FC3: 84 -> 10 ----
    for (int idx = tid; idx < 320; idx += 256) {
        const int j = idx % 10, im = idx / 10;
        float a = big[8192 + 840 + j];
#pragma unroll 4
        for (int i = 0; i < 84; ++i)
            a += big[i * 36 + im] * big[8192 + i * 10 + j];
        out[(img0 + im) * 10 + j] = a;
    }
}

extern "C" void kernel_launch(void* const* d_in, const int* in_sizes, int n_in,
                              void* d_out, int out_size, void* d_ws, size_t ws_size,
                              hipStream_t stream) {
    const float* x   = (const float*)d_in[0];
    const float* W1  = (const float*)d_in[1];
    const float* b1  = (const float*)d_in[2];
    const float* W2  = (const float*)d_in[3];
    const float* b2  = (const float*)d_in[4];
    const float* L1  = (const float*)d_in[5];
    const float* Lb1 = (const float*)d_in[6];
    const float* L2  = (const float*)d_in[7];
    const float* Lb2 = (const float*)d_in[8];
    const float* L3  = (const float*)d_in[9];
    const float* Lb3 = (const float*)d_in[10];
    float* out = (float*)d_out;

    const int B = in_sizes[0] / 784;  // 8192

    char* ws = (char*)d_ws;
    float* w6  = (float*)ws;                        // 1.9KB (pad 4KB)
    float* w2q = (float*)(ws + 4096);               // 20KB (pad 32KB)
    float* L2p = (float*)(ws + 4096 + 32768);       // 42.2KB (pad 64KB)
    float* h2i = (float*)(ws + 4096 + 32768 + 65536);

    hipLaunchKernelGGL(k_prep, dim3(61), dim3(256), 0, stream, W1, W2, L2, w6, w2q, L2p);
    hipLaunchKernelGGL(k_convs, dim3(B / 8), dim3(512), 0, stream, x, w6, b1, w2q, b2, h2i);
    hipLaunchKernelGGL(k_fc, dim3(B / 32), dim3(256), 0, stream,
                       h2i, L1, Lb1, L2p, Lb2, L3, Lb3, out);
}